// Round 18
// baseline (474.987 us; speedup 1.0000x reference)
//
#include <hip/hip_runtime.h>
#include <hip/hip_bf16.h>
#include <math.h>

typedef __attribute__((ext_vector_type(8))) short short8;
typedef __attribute__((ext_vector_type(16))) float f32x16;

__device__ inline f32x16 mfma32(short8 a, short8 b, f32x16 c) {
    return __builtin_amdgcn_mfma_f32_32x32x16_bf16(a, b, c, 0, 0, 0);
}

__device__ inline void bsplit(float x, ushort& h, ushort& l) {
    __hip_bfloat16 bh = __float2bfloat16(x);
    float hf = __bfloat162float(bh);
    __hip_bfloat16 bl = __float2bfloat16(x - hf);
    h = *reinterpret_cast<ushort*>(&bh);
    l = *reinterpret_cast<ushort*>(&bl);
}

// inverse of the IEEE-monotone u32 map mp = db ^ (0x80000000 | (db>>31 arith))
__device__ inline float unmap_f(unsigned int mp) {
    unsigned int db = mp ^ (0x80000000u | (unsigned int)((int)(~mp) >> 31));
    return __uint_as_float(db);
}

// ---------------------------------------------------------------------------
// Fused weight convert: all five W[o][k] -> hi/lo bf16 planes in one launch
__global__ void k_wsplit_all(
    const float* __restrict__ w3s, const float* __restrict__ hw1,
    const float* __restrict__ hw2, const float* __restrict__ hw3,
    const float* __restrict__ hw4,
    ushort* __restrict__ w3h, ushort* __restrict__ w3l,
    ushort* __restrict__ w1eh, ushort* __restrict__ w1el,
    ushort* __restrict__ w2h, ushort* __restrict__ w2l,
    ushort* __restrict__ wh3h, ushort* __restrict__ wh3l,
    ushort* __restrict__ w4h, ushort* __restrict__ w4l) {
    int i = blockIdx.x * 256 + threadIdx.x;
    const float* src; int rs, co, Ms, K, base; ushort *hi, *lo;
    if (i < 32768)       { src = w3s; rs = 64;   co = 0;   Ms = 512; K = 64;  hi = w3h;  lo = w3l;  base = 0; }
    else if (i < 65536)  { src = hw1; rs = 1088; co = 512; Ms = 512; K = 64;  hi = w1eh; lo = w1el; base = 32768; }
    else if (i < 196608) { src = hw2; rs = 512;  co = 0;   Ms = 256; K = 512; hi = w2h;  lo = w2l;  base = 65536; }
    else if (i < 229376) { src = hw3; rs = 256;  co = 0;   Ms = 128; K = 256; hi = wh3h; lo = wh3l; base = 196608; }
    else if (i < 233472) { src = hw4; rs = 128;  co = 0;   Ms = 6;   K = 128; hi = w4h;  lo = w4l;  base = 229376; }
    else return;
    int li = i - base;
    int o = li / K, k = li - o * K;
    float x = (o < Ms) ? src[(size_t)o * rs + co + k] : 0.f;
    ushort h, l;
    bsplit(x, h, l);
    hi[li] = h; lo[li] = l;
}

// ---------------------------------------------------------------------------
// Layer 1 stats
__global__ void k_stats1(const float* __restrict__ pts, const float* __restrict__ w1,
                         const float* __restrict__ b1, float* __restrict__ part1) {
    __shared__ float sw[256];
    __shared__ float wred[2][4][64];
    int t = threadIdx.x;
    if (t < 192) sw[t] = w1[t];
    if (t < 64) sw[192 + t] = b1[t];
    __syncthreads();
    int g = blockIdx.x * 256 + t;
    float p0 = pts[g*3], p1 = pts[g*3+1], p2 = pts[g*3+2];
    int lane = t & 63, wv = t >> 6;
    for (int c = 0; c < 64; c++) {
        float y = fmaf(sw[c*3+2], p2, fmaf(sw[c*3+1], p1, fmaf(sw[c*3], p0, sw[192+c])));
        float s = y, q = y * y;
        #pragma unroll
        for (int o = 32; o > 0; o >>= 1) { s += __shfl_down(s, o); q += __shfl_down(q, o); }
        if (lane == 0) { wred[0][wv][c] = s; wred[1][wv][c] = q; }
    }
    __syncthreads();
    if (t < 64) {
        float s = wred[0][0][t] + wred[0][1][t] + wred[0][2][t] + wred[0][3][t];
        float q = wred[1][0][t] + wred[1][1][t] + wred[1][2][t] + wred[1][3][t];
        part1[blockIdx.x * 128 + t] = s;
        part1[blockIdx.x * 128 + 64 + t] = q;
    }
}

// Generic BN-stat finalize
__global__ void k_fin(const float* __restrict__ part, int count, int stride, int sqoff,
                      const float* __restrict__ g, const float* __restrict__ be,
                      float* __restrict__ sout, float* __restrict__ tout) {
    int c = blockIdx.x, t = threadIdx.x;
    float s = 0.f, q = 0.f;
    for (int w = t; w < count; w += 256) { s += part[(size_t)w*stride + c]; q += part[(size_t)w*stride + sqoff + c]; }
    __shared__ float rs[4], rq[4];
    int lane = t & 63, wv = t >> 6;
    #pragma unroll
    for (int o = 32; o > 0; o >>= 1) { s += __shfl_down(s, o); q += __shfl_down(q, o); }
    if (lane == 0) { rs[wv] = s; rq[wv] = q; }
    __syncthreads();
    if (t == 0) {
        s = rs[0] + rs[1] + rs[2] + rs[3];
        q = rq[0] + rq[1] + rq[2] + rq[3];
        float mean = s / 65536.f;
        float var = q / 65536.f - mean * mean;
        float sc = g[c] * rsqrtf(var + 1e-5f);
        sout[c] = sc;
        tout[c] = be[c] - mean * sc;
    }
}

// l_feat bf16 hi/lo planes, layout [n][64]
__global__ void k_lfeat2(const float* __restrict__ pts, const float* __restrict__ w1,
                         const float* __restrict__ b1, const float* __restrict__ s1,
                         const float* __restrict__ t1, ushort* __restrict__ lfh,
                         ushort* __restrict__ lfl) {
    __shared__ float sw[256], ss[64], st[64];
    int t = threadIdx.x;
    if (t < 192) sw[t] = w1[t];
    if (t < 64) { sw[192+t] = b1[t]; ss[t] = s1[t]; st[t] = t1[t]; }
    __syncthreads();
    int g = blockIdx.x * 256 + t;
    float p0 = pts[g*3], p1 = pts[g*3+1], p2 = pts[g*3+2];
    for (int c0 = 0; c0 < 64; c0 += 8) {
        union { short8 v; ushort u[8]; } H, L;
        #pragma unroll
        for (int j = 0; j < 8; j++) {
            int c = c0 + j;
            float y = fmaf(sw[c*3+2], p2, fmaf(sw[c*3+1], p1, fmaf(sw[c*3], p0, sw[192+c])));
            float a = fmaxf(fmaf(ss[c], y, st[c]), 0.f);
            bsplit(a, H.u[j], L.u[j]);
        }
        *(short8*)(lfh + (size_t)g*64 + c0) = H.v;
        *(short8*)(lfl + (size_t)g*64 + c0) = L.v;
    }
}

// ---------------------------------------------------------------------------
// K=64 MFMA GEMM: MODE 0 = conv3 (stats s/q/max + y38), MODE 1 = h1 stats
template<int MODE>
__global__ __launch_bounds__(256, 2) void k_gemm64(
    const ushort* __restrict__ Bhi, const ushort* __restrict__ Blo,
    const ushort* __restrict__ Ahi, const ushort* __restrict__ Alo,
    const float* __restrict__ bias, const float* __restrict__ A1,
    const float* __restrict__ G1, const float* __restrict__ mb,
    float* __restrict__ part, float* __restrict__ y38) {
    __shared__ ushort sbh[128*64], sbl[128*64];
    __shared__ float sPb[512], sPa[512];
    int t = threadIdx.x, pb = blockIdx.x;
    int gn0 = pb * 128, b = pb >> 5;
    for (int i = t; i < 512; i += 256) {
        float bb = bias[i];
        if (MODE) bb += G1[(b<<9) + i];
        sPb[i] = bb;
        sPa[i] = MODE ? A1[i] : 0.f;
    }
    for (int it = 0; it < 4; it++) {
        int s = it*256 + t;
        int n = s >> 3, c16 = s & 7;
        int off = (c16*16) ^ ((n & 7) << 4);
        int sb8 = (it*256 + (t & 192)) * 8;
        __builtin_amdgcn_global_load_lds((const char*)Bhi + (size_t)(gn0+n)*128 + off, &sbh[sb8], 16, 0, 0);
        __builtin_amdgcn_global_load_lds((const char*)Blo + (size_t)(gn0+n)*128 + off, &sbl[sb8], 16, 0, 0);
    }
    __syncthreads();
    int lane = t & 63, wv = t >> 6, m = lane & 31, kg = lane >> 5;
    for (int ct = 0; ct < 4; ct++) {
        int ch0 = wv*128 + ct*32;
        short8 ah[4], al[4];
        #pragma unroll
        for (int ks = 0; ks < 4; ks++) {
            ah[ks] = *(const short8*)(Ahi + (size_t)(ch0+m)*64 + ks*16 + kg*8);
            al[ks] = *(const short8*)(Alo + (size_t)(ch0+m)*64 + ks*16 + kg*8);
        }
        float ssum[16] = {}, ssq[16] = {}, smx[16];
        #pragma unroll
        for (int r = 0; r < 16; r++) smx[r] = -__builtin_inff();
        for (int pt = 0; pt < 4; pt++) {
            int n = pt*32 + m;
            f32x16 acc = {};
            #pragma unroll
            for (int ks = 0; ks < 4; ks++) {
                int off = ((ks*16 + kg*8)*2) ^ ((n & 7) << 4);
                short8 bh = *(const short8*)((const char*)sbh + n*128 + off);
                short8 bl = *(const short8*)((const char*)sbl + n*128 + off);
                acc = mfma32(ah[ks], bh, acc);
                acc = mfma32(ah[ks], bl, acc);
                acc = mfma32(al[ks], bh, acc);
            }
            float mval = MODE ? mb[gn0 + n] : 0.f;
            #pragma unroll
            for (int r = 0; r < 16; r++) {
                int chr = ch0 + (r&3) + 8*(r>>2) + 4*kg;
                float v = acc[r] + sPb[chr] + (MODE ? sPa[chr]*mval : 0.f);
                ssum[r] += v; ssq[r] = fmaf(v, v, ssq[r]);
                if (MODE == 0) {
                    smx[r] = fmaxf(smx[r], v);
                    if (wv == 0 && ct == 0 && r < 4) {
                        int c8 = (r&3) + 4*kg;  // 0..7
                        y38[(size_t)c8*65536 + gn0 + n] = v;
                    }
                }
            }
        }
        #pragma unroll
        for (int r = 0; r < 16; r++) {
            float s = ssum[r], q = ssq[r], x = smx[r];
            #pragma unroll
            for (int o = 16; o > 0; o >>= 1) {
                s += __shfl_xor(s, o); q += __shfl_xor(q, o);
                if (MODE == 0) x = fmaxf(x, __shfl_xor(x, o));
            }
            if (m == 0) {
                int chr = ch0 + (r&3) + 8*(r>>2) + 4*kg;
                if (MODE == 0) {
                    part[(size_t)pb*1536 + chr] = s;
                    part[(size_t)pb*1536 + 512 + chr] = q;
                    part[(size_t)pb*1536 + 1024 + chr] = x;
                } else {
                    part[(size_t)pb*1024 + chr] = s;
                    part[(size_t)pb*1024 + 512 + chr] = q;
                }
            }
        }
    }
}

// gmax[b,c] = relu(s3*max + t3); part3 blocks 32 per batch
__global__ void k_fin3b(const float* __restrict__ part3, const float* __restrict__ s3,
                        const float* __restrict__ t3, float* __restrict__ gmaxb) {
    int b = blockIdx.x, c = threadIdx.x;
    float mx = -__builtin_inff();
    for (int i = 0; i < 32; i++) mx = fmaxf(mx, part3[(size_t)(b*32+i)*1536 + 1024 + c]);
    gmaxb[(b<<9)+c] = fmaxf(fmaf(s3[c], mx, t3[c]), 0.f);
}

// A1/G1 v2: coalesced float4 reads; summation order identical to v1
__global__ void k_a1g1(const float* __restrict__ hw1, const float* __restrict__ gmaxb,
                       float* __restrict__ A1, float* __restrict__ G1) {
    __shared__ float sg[512];
    int blk = blockIdx.x, t = threadIdx.x;
    if (blk < 32) {
        int b = blk >> 1;
        for (int i = t; i < 512; i += 256) sg[i] = gmaxb[(b<<9)+i];
        __syncthreads();
        int o = (blk & 1)*256 + t;
        float s = 0.f;
        for (int c4 = 0; c4 < 128; c4++) {
            float4 w = *(const float4*)&hw1[(size_t)o*1088 + 576 + c4*4];
            s = fmaf(w.x, sg[c4*4],   s);
            s = fmaf(w.y, sg[c4*4+1], s);
            s = fmaf(w.z, sg[c4*4+2], s);
            s = fmaf(w.w, sg[c4*4+3], s);
        }
        G1[(b<<9)+o] = s;
    } else {
        int o = (blk - 32)*256 + t;
        float s = 0.f;
        for (int c4 = 0; c4 < 128; c4++) {
            float4 w = *(const float4*)&hw1[(size_t)o*1088 + c4*4];
            s += w.x; s += w.y; s += w.z; s += w.w;
        }
        A1[o] = s;
    }
}

// ---------------------------------------------------------------------------
// Sort each batch's points by x; pair-indexed bitonic (2048 pairs/stage).
__global__ __launch_bounds__(1024) void k_sortx(
    const float* __restrict__ pts, float4* __restrict__ sxp, int* __restrict__ sidxg) {
    __shared__ unsigned long long key[4096];   // 32 KB
    int t = threadIdx.x, b = blockIdx.x;
    const float* pb = pts + (size_t)b * 4096 * 3;
    for (int i = t; i < 4096; i += 1024) {
        float x = pb[i*3];
        unsigned int xb = __float_as_uint(x);
        unsigned int mp = xb ^ (0x80000000u | (unsigned int)((int)xb >> 31));
        key[i] = ((unsigned long long)mp << 32) | (unsigned int)i;
    }
    __syncthreads();
    for (int k = 2; k <= 4096; k <<= 1) {
        for (int j = k >> 1; j >= 1; j >>= 1) {
            #pragma unroll 2
            for (int q = t; q < 2048; q += 1024) {
                int i = ((q & ~(j-1)) << 1) | (q & (j-1));
                int p = i | j;
                bool up = ((i & k) == 0);
                unsigned long long a = key[i], c = key[p];
                if ((c < a) == up) { key[i] = c; key[p] = a; }
            }
            __syncthreads();
        }
    }
    for (int i = t; i < 4096; i += 1024) {
        int orig = (int)(key[i] & 0xffffffffull);
        float c0 = pb[orig*3], c1 = pb[orig*3+1], c2 = pb[orig*3+2];
        float cw = __fadd_rn(__fadd_rn(__fmul_rn(c0,c0), __fmul_rn(c1,c1)), __fmul_rn(c2,c2));
        sxp[(size_t)b*4096 + i] = make_float4(c0, c1, c2, cw);
        sidxg[(size_t)b*4096 + i] = orig;
    }
}

// ---------------------------------------------------------------------------
// KNN v13: x-sorted windowed scan, queries grouped by SORTED position.
// Wave handles 4 x-adjacent sorted queries (2 passes); they share one
// expanding candidate window (span of 4 sorted slots). Exactness identical
// to v12 (passed r17): side pruned only when computed (dx)^2 > thr+MARG for
// ALL live queries of that side; per-query lex (d, orig_idx) gate/insert;
// dist arithmetic bitwise identical to reference. mbuf scatter via query's
// orig idx (sorted positions are a permutation -> every slot written once).
__global__ __launch_bounds__(1024, 8)
void k_knn(const float4* __restrict__ sxp, const int* __restrict__ sidxg,
           const float* __restrict__ y38, const float* __restrict__ s3,
           const float* __restrict__ t3, float* __restrict__ mbuf) {
    __shared__ float4 sp[4096];   // 64 KB sorted candidates
    __shared__ int sid[4096];     // 16 KB orig indices
    int t = threadIdx.x, blk = blockIdx.x;
    int b = blk >> 5;
    int lane = t & 63, wv = t >> 6;
    for (int i = t; i < 4096; i += 1024) {
        sp[i] = sxp[(size_t)b*4096 + i];
        sid[i] = sidxg[(size_t)b*4096 + i];
    }
    __syncthreads();
    const int NINF = 0xff800000;  // -inf bits
    const float MARG = 1e-4f;
    for (int pass = 0; pass < 2; ++pass) {
        int qbase = (blk & 31) * 128 + pass*64 + wv*4;   // SORTED position
        float q0[4], q1[4], q2[4], qx2[4]; int qid[4];
        #pragma unroll
        for (int qi = 0; qi < 4; qi++) {
            float4 qp = sp[qbase + qi];
            q0[qi] = qp.x; q1[qi] = qp.y; q2[qi] = qp.z; qx2[qi] = qp.w;
            qid[qi] = sid[qbase + qi];
        }
        int wlo = qbase & ~63, whi = (qbase & ~63) + 64;
        float sd[4]; unsigned int si[4]; float thr[4]; unsigned int thri[4];
        // ---- initial window: bitonic full sort per query on (d, orig idx)
        {
            float4 cp = sp[wlo + lane];
            int idc = sid[wlo + lane];
            #pragma unroll
            for (int qi = 0; qi < 4; qi++) {
                float dot = __fadd_rn(__fadd_rn(__fmul_rn(q0[qi],cp.x), __fmul_rn(q1[qi],cp.y)), __fmul_rn(q2[qi],cp.z));
                float d = __fsub_rn(__fadd_rn(qx2[qi], cp.w), __fmul_rn(2.f, dot));
                unsigned int db = __float_as_uint(d);
                unsigned int mp = db ^ (0x80000000u | (unsigned int)((int)db >> 31));
                unsigned long long key = ((unsigned long long)mp << 32) | (unsigned int)idc;
                #pragma unroll
                for (int k = 2; k <= 64; k <<= 1) {
                    #pragma unroll
                    for (int jj = k >> 1; jj >= 1; jj >>= 1) {
                        unsigned long long pk = __shfl_xor(key, jj);
                        bool up = ((lane & k) == 0);
                        bool lower = ((lane & jj) == 0);
                        bool keepmin = (lower == up);
                        unsigned long long mn = (pk < key) ? pk : key;
                        unsigned long long mx = (pk < key) ? key : pk;
                        key = keepmin ? mn : mx;
                    }
                }
                sd[qi] = unmap_f((unsigned int)(key >> 32));
                si[qi] = (unsigned int)key;
                thr[qi] = __shfl(sd[qi], 7);
                thri[qi] = __shfl(si[qi], 7);
            }
        }
        // ---- expanding window scan (shared across the 4 queries) ----
        while (true) {
            bool aliveL = (wlo > 0);
            float blm = __builtin_inff();
            if (aliveL) {
                float xb = sp[wlo-1].x;
                bool any = false;
                #pragma unroll
                for (int qi = 0; qi < 4; qi++) {
                    float dl = __fsub_rn(q0[qi], xb);
                    float d2 = __fmul_rn(dl, dl);
                    if (d2 <= thr[qi] + MARG) any = true;
                    blm = fminf(blm, d2);
                }
                aliveL = any;
            }
            bool aliveR = (whi < 4096);
            float brm = __builtin_inff();
            if (aliveR) {
                float xb = sp[whi].x;
                bool any = false;
                #pragma unroll
                for (int qi = 0; qi < 4; qi++) {
                    float dr = __fsub_rn(xb, q0[qi]);
                    float d2 = __fmul_rn(dr, dr);
                    if (d2 <= thr[qi] + MARG) any = true;
                    brm = fminf(brm, d2);
                }
                aliveR = any;
            }
            if (!aliveL && !aliveR) break;
            bool goL = aliveL && (!aliveR || blm <= brm);
            int base;
            if (goL) { base = wlo - 64; wlo = (base < 0) ? 0 : base; }
            else     { base = whi; whi = (whi + 64 > 4096) ? 4096 : whi + 64; }
            int ii = base + lane;
            bool valid = (ii >= 0) && (ii < 4096);
            int ic = valid ? ii : 0;
            float4 cp = sp[ic];
            int idc = sid[ic];
            #pragma unroll
            for (int qi = 0; qi < 4; qi++) {
                float dot = __fadd_rn(__fadd_rn(__fmul_rn(q0[qi],cp.x), __fmul_rn(q1[qi],cp.y)), __fmul_rn(q2[qi],cp.z));
                float d = __fsub_rn(__fadd_rn(qx2[qi], cp.w), __fmul_rn(2.f, dot));
                if (!valid) d = __builtin_inff();
                unsigned long long mask = __ballot(d < thr[qi] || (d == thr[qi] && (unsigned int)idc < thri[qi]));
                if (mask != 0ull) {
                    do {
                        int src = __ffsll(mask) - 1;
                        float db = __uint_as_float(__builtin_amdgcn_readlane(__float_as_uint(d), src));
                        unsigned int idb = (unsigned int)__builtin_amdgcn_readlane(idc, src);
                        float pd = __int_as_float(__builtin_amdgcn_update_dpp(
                            NINF, __float_as_int(sd[qi]), 0x111, 0xf, 0xf, false));  // row_shr:1
                        unsigned int pi = (unsigned int)__builtin_amdgcn_update_dpp(
                            0, (int)si[qi], 0x111, 0xf, 0xf, false);
                        bool keep = (sd[qi] < db) || (sd[qi] == db && si[qi] < idb);
                        bool pk   = (pd < db) || (pd == db && pi < idb);
                        sd[qi] = keep ? sd[qi] : (pk ? db : pd);
                        si[qi] = keep ? si[qi] : (pk ? idb : pi);
                        mask &= (mask - 1ull);
                    } while (mask != 0ull);
                    thr[qi] = __shfl(sd[qi], 7);
                    thri[qi] = __shfl(si[qi], 7);
                }
            }
        }
        // epilogue: m = max_k relu(s3[k]*y3[k, idx_k]+t3[k]); slot k in lane k
        if (lane < 8) {
            #pragma unroll
            for (int qi = 0; qi < 4; qi++) {
                float y = y38[(size_t)lane*65536 + (b<<12) + (si[qi] & 4095)];
                float mv = fmaxf(fmaf(s3[lane], y, t3[lane]), 0.f);
                mv = fmaxf(mv, __shfl_xor(mv, 1));
                mv = fmaxf(mv, __shfl_xor(mv, 2));
                mv = fmaxf(mv, __shfl_xor(mv, 4));
                if (lane == 0) mbuf[(b<<12) + qid[qi]] = mv;
            }
        }
    }
}

// ---------------------------------------------------------------------------
// h2 FUSED: per 64-ch K-chunk, phase-1 computes a1 into swizzled LDS;
// phase-2 accumulates pre2 = hw2 @ a1. grid 512 x 256thr, 128 pts/block.
__global__ __launch_bounds__(256, 2) void k_h2f(
    const ushort* __restrict__ lfh, const ushort* __restrict__ lfl,
    const ushort* __restrict__ W1hi, const ushort* __restrict__ W1lo,
    const ushort* __restrict__ W2hi, const ushort* __restrict__ W2lo,
    const float* __restrict__ hb1, const float* __restrict__ A1g,
    const float* __restrict__ G1g, const float* __restrict__ mb,
    const float* __restrict__ sh1, const float* __restrict__ th1,
    const float* __restrict__ hb2,
    float* __restrict__ pre2, float* __restrict__ parth2) {
    __shared__ ushort sLh[128*64], sLl[128*64];   // lf tile, 16+16 KB
    __shared__ ushort a1h[128*64], a1l[128*64];   // a1 chunk, 16+16 KB
    __shared__ float sP0[512], sP1[512], sSh[512];
    int t = threadIdx.x, pb = blockIdx.x;
    int gn0 = pb * 128, b = pb >> 5;
    for (int i = t; i < 512; i += 256) {
        float s = sh1[i];
        sP0[i] = fmaf(s, hb1[i] + G1g[(b<<9)+i], th1[i]);
        sP1[i] = s * A1g[i];
        sSh[i] = s;
    }
    for (int it = 0; it < 4; it++) {
        int s = it*256 + t;
        int n = s >> 3, c16 = s & 7;
        int off = (c16*16) ^ ((n & 7) << 4);
        int sb8 = (it*256 + (t & 192)) * 8;
        __builtin_amdgcn_global_load_lds((const char*)lfh + (size_t)(gn0+n)*128 + off, &sLh[sb8], 16, 0, 0);
        __builtin_amdgcn_global_load_lds((const char*)lfl + (size_t)(gn0+n)*128 + off, &sLl[sb8], 16, 0, 0);
    }
    __syncthreads();
    int lane = t & 63, wv = t >> 6, m = lane & 31, kg = lane >> 5;
    int pn = wv*32 + m;
    float mval = mb[gn0 + pn];
    f32x16 acc0[4] = {}, acc1[4] = {};
    for (int ch = 0; ch < 8; ch++) {
        #pragma unroll
        for (int cht = 0; cht < 2; cht++) {
            int cch = ch*64 + cht*32;
            f32x16 acc = {};
            #pragma unroll
            for (int ks = 0; ks < 4; ks++) {
                short8 ah = *(const short8*)(W1hi + (size_t)(cch+m)*64 + ks*16 + kg*8);
                short8 al = *(const short8*)(W1lo + (size_t)(cch+m)*64 + ks*16 + kg*8);
                int off = ((ks*16 + kg*8)*2) ^ ((m & 7) << 4);
                short8 bh = *(const short8*)((const char*)sLh + pn*128 + off);
                short8 bl = *(const short8*)((const char*)sLl + pn*128 + off);
                acc = mfma32(ah, bh, acc);
                acc = mfma32(ah, bl, acc);
                acc = mfma32(al, bh, acc);
            }
            #pragma unroll
            for (int q = 0; q < 4; q++) {
                ushort hs[4], ls[4];
                #pragma unroll
                for (int i = 0; i < 4; i++) {
                    int r = q*4 + i;
                    int chr = cch + i + 8*q + 4*kg;
                    float a = fmaxf(fmaf(sSh[chr], acc[r], sP0[chr] + sP1[chr]*mval), 0.f);
                    bsplit(a, hs[i], ls[i]);
                }
                int chb = cht*32 + 8*q + 4*kg;
                int off = (chb*2) ^ ((m & 7) << 4);
                uint2 vh, vl;
                vh.x = (uint)hs[0] | ((uint)hs[1] << 16); vh.y = (uint)hs[2] | ((uint)hs[3] << 16);
                vl.x = (uint)ls[0] | ((uint)ls[1] << 16); vl.y = (uint)ls[2] | ((uint)ls[3] << 16);
                *(uint2*)((char*)a1h + pn*128 + off) = vh;
                *(uint2*)((char*)a1l + pn*128 + off) = vl;
            }
        }
        __syncthreads();
        #pragma unroll
        for (int ks = 0; ks < 4; ks++) {
            int koc = ks*16 + kg*8;
            int kglob = ch*64 + koc;
            short8 w0h = *(const short8*)(W2hi + (size_t)(wv*64+m)*512 + kglob);
            short8 w0l = *(const short8*)(W2lo + (size_t)(wv*64+m)*512 + kglob);
            short8 w1h = *(const short8*)(W2hi + (size_t)(wv*64+32+m)*512 + kglob);
            short8 w1l = *(const short8*)(W2lo + (size_t)(wv*64+32+m)*512 + kglob);
            #pragma unroll
            for (int pt = 0; pt < 4; pt++) {
                int n = pt*32 + m;
                int off = (koc*2) ^ ((n & 7) << 4);
                short8 bh = *(const short8*)((const char*)a1h + n*128 + off);
                short8 bl = *(const short8*)((const char*)a1l + n*128 + off);
                acc0[pt] = mfma32(w0h, bh, acc0[pt]);
                acc1[pt] = mfma32(w1h, bh, acc1[pt]);
                acc0[pt] = mfma32(w0h, bl, acc0[pt]);
                acc1[pt] = mfma32(w1h, bl, acc1[pt]);
                acc0[pt] = mfma32(w0l, bh, acc0[pt]);
                acc1[pt] = mfma32(w1l, bh, acc1[pt]);
            }
        }
        __syncthreads();
    }
    #pragma unroll
    for (int ti = 0; ti < 2; ti++) {
        #pragma unroll
        for (int r = 0; r < 16; r++) {
            int chr = wv*64 + ti*32 + (r&3) + 8*(r>>2) + 4*kg;
            float hb = hb2[chr];
            float s = 0.f, q = 0.f;
            #pragma unroll
            for (int pt = 0; pt < 4; pt++) {
                float v = (ti ? acc1[pt][r] : acc0[pt][r]) + hb;
                pre2[(size_t)chr*65536 + gn0 + pt*32 + m] = v;
                s += v; q = fmaf(v, v, q);
            }
            #pragma unroll
            for (int o = 16; o > 0; o >>= 1) { s += __shfl_xor(s, o); q += __shfl_xor(q, o); }
            if (m == 0) {
                parth2[(size_t)pb*512 + chr] = s;
                parth2[(size_t)pb*512 + 256 + chr] = q;
            }
        }
    }
}

// ---------------------------------------------------------------------------
// h3 stats + pre3 materialize: pre3 = hw3 @ a2 + hb3 written to global [c][n].
__global__ __launch_bounds__(256, 2) void k_h3s(
    const float* __restrict__ pre2, const float* __restrict__ sh2,
    const float* __restrict__ th2,
    const ushort* __restrict__ W3hi, const ushort* __restrict__ W3lo,
    const float* __restrict__ hb3, float* __restrict__ parth3,
    float* __restrict__ pre3) {
    __shared__ ushort sbh[32*256], sbl[32*256];   // 16+16 KB
    __shared__ float ft[128*36];                  // 18 KB padded fp32 tile
    __shared__ float sS2[256], sT2[256];
    int t = threadIdx.x, pb = blockIdx.x;
    sS2[t] = sh2[t]; sT2[t] = th2[t];
    int lane = t & 63, wv = t >> 6, m = lane & 31, kg = lane >> 5;
    int ch0 = wv * 32;
    int cn = t & 31, cgq = t >> 5;
    float bhr[16];
    #pragma unroll
    for (int r = 0; r < 16; r++) bhr[r] = hb3[ch0 + (r&3) + 8*(r>>2) + 4*kg];
    float ssum[16] = {}, ssq[16] = {};
    for (int pt = 0; pt < 4; pt++) {
        int gn0 = pb*128 + pt*32;
        for (int h = 0; h < 2; h++) {
            __syncthreads();
            #pragma unroll
            for (int i = 0; i < 4; i++) {
                int idx = i*256 + t;
                int row = idx >> 3, c4 = idx & 7;
                float4 v = *(const float4*)(pre2 + (size_t)(h*128+row)*65536 + gn0 + c4*4);
                float* dst = &ft[row*36 + c4*4];
                dst[0] = v.x; dst[1] = v.y; dst[2] = v.z; dst[3] = v.w;
            }
            __syncthreads();
            #pragma unroll
            for (int i4 = 0; i4 < 4; i4++) {
                int cl0 = cgq*16 + i4*4;
                int cg0 = h*128 + cl0;
                ushort hs[4], ls[4];
                #pragma unroll
                for (int i = 0; i < 4; i++) {
                    float v = fmaxf(fmaf(sS2[cg0+i], ft[(cl0+i)*36 + cn], sT2[cg0+i]), 0.f);
                    bsplit(v, hs[i], ls[i]);
                }
                int off = cn*512 + (((cg0 >> 3)*16) ^ ((cn & 15) << 4)) + (cg0 & 7)*2;
                uint2 vh, vl;
                vh.x = (uint)hs[0] | ((uint)hs[1] << 16); vh.y = (uint)hs[2] | ((uint)hs[3] << 16);
                vl.x = (uint)ls[0] | ((uint)ls[1] << 16); vl.y = (uint)ls[2] | ((uint)ls[3] << 16);
                *(uint2*)((char*)sbh + off) = vh;
                *(uint2*)((char*)sbl + off) = vl;
            }
        }
        __syncthreads();
        f32x16 acc = {};
        for (int ks = 0; ks < 16; ks++) {
            int ko = ks*16 + kg*8;
            int off = (ko*2) ^ ((m & 15) << 4);
            short8 bh = *(const short8*)((const char*)sbh + m*512 + off);
            short8 bl = *(const short8*)((const char*)sbl + m*512 + off);
            short8 ah = *(const short8*)(W3hi + (size_t)(ch0+m)*256 + ko);
            short8 al = *(const short8*)(W3lo + (size_t)(ch0+m)*256 + ko);
            acc = mfma32(ah, bh, acc);
            acc = mfma32(ah, bl, acc);
            acc = mfma32(al, bh, acc);
        }
        #pragma unroll
        for (int r = 0; r < 16; r++) {
            float v = acc[r] + bhr[r];
            int chr = ch0 + (r&3) + 8*(r>>2) + 4*kg;
            pre3[(size_t)chr*65536 + gn0 + m] = v;
            ssum[r] += v; ssq[r] = fmaf(v, v, ssq[r]);
        }
    }
    #pragma unroll
    for (int r = 0; r < 16; r++) {
        float s = ssum[r], q = ssq[r];
        #pragma unroll
        for (int o = 16; o > 0; o >>= 1) { s += __shfl_xor(s, o); q += __shfl_xor(q, o); }
        if (m == 0) {
            int chr = ch0 + (r&3) + 8*(r>>2) + 4*kg;
            parth3[(size_t)pb*256 + chr] = s;
            parth3[(size_t)pb*256 + 128 + chr] = q;
        }
    }
}

// ---------------------------------------------------------------------------
// h4 light: a3 = relu(sh3*pre3 + th3); out = hw4 @ a3 + hb4 (fp32 dot).
__global__ __launch_bounds__(256) void k_h4l(
    const float* __restrict__ pre3, const float* __restrict__ sh3,
    const float* __restrict__ th3, const float* __restrict__ hw4,
    const float* __restrict__ hb4, float* __restrict__ out) {
    __shared__ float a3[128*66];     // padded [c][66]
    __shared__ float sW[6*128];
    __shared__ float sB[8];
    int t = threadIdx.x, pb = blockIdx.x;
    int n0 = pb * 64;
    for (int i = t; i < 768; i += 256) sW[i] = hw4[i];
    if (t < 6) sB[t] = hb4[t];
    #pragma unroll
    for (int k = 0; k < 32; k++) {
        int i = k*256 + t;
        int c = i >> 6, col = i & 63;
        float v = pre3[(size_t)c*65536 + n0 + col];
        a3[c*66 + col] = fmaxf(fmaf(sh3[c], v, th3[c]), 0.f);
    }
    __syncthreads();
    int p = t & 63, grp = t >> 6;
    if (grp < 3) {
        float a0 = sB[grp*2], a1 = sB[grp*2+1];
        const float* w0 = &sW[(grp*2)*128];
        const float* w1 = &sW[(grp*2+1)*128];
        #pragma unroll 4
        for (int c = 0; c < 128; c++) {
            float x = a3[c*66 + p];
            a0 = fmaf(w0[c], x, a0);
            a1 = fmaf(w1[c], x, a1);
        }
        out[(size_t)(n0+p)*6 + grp*2]     = a0;
        out[(size_t)(n0+p)*6 + grp*2 + 1] = a1;
    }
}

extern "C" void kernel_launch(void* const* d_in, const int* in_sizes, int n_in,
                              void* d_out, int out_size, void* d_ws, size_t ws_size,
                              hipStream_t stream) {
    const float* pts  = (const float*)d_in[0];
    const float* w1   = (const float*)d_in[1];
    const float* b1   = (const float*)d_in[2];
    const float* g1   = (const float*)d_in[3];
    const float* be1  = (const float*)d_in[4];
    const float* w3   = (const float*)d_in[5];
    const float* b3   = (const float*)d_in[6];
    const float* g3   = (const float*)d_in[7];
    const float* be3  = (const float*)d_in[8];
    const float* hw1  = (const float*)d_in[9];
    const float* hb1  = (const float*)d_in[10];
    const float* hg1  = (const float*)d_in[11];
    const float* hbe1 = (const float*)d_in[12];
    const float* hw2  = (const float*)d_in[13];
    const float* hb2  = (const float*)d_in[14];
    const float* hg2  = (const float*)d_in[15];
    const float* hbe2 = (const float*)d_in[16];
    const float* hw3  = (const float*)d_in[17];
    const float* hb3  = (const float*)d_in[18];
    const float* hg3  = (const float*)d_in[19];
    const float* hbe3 = (const float*)d_in[20];
    const float* hw4  = (const float*)d_in[21];
    const float* hb4  = (const float*)d_in[22];
    (void)in_sizes; (void)n_in; (void)out_size; (void)ws_size;

    float* W = (float*)d_ws;
    size_t off = 0;
    auto alloc = [&](size_t n) { float* p = W + off; off += n; return p; };
    auto allocU = [&](size_t nshorts) { return (ushort*)alloc((nshorts + 1) / 2); };

    ushort* lfh  = allocU(65536UL*64);
    ushort* lfl  = allocU(65536UL*64);
    ushort* w3h  = allocU(512*64);  ushort* w3l  = allocU(512*64);
    ushort* w1eh = allocU(512*64);  ushort* w1el = allocU(512*64);
    ushort* w2h  = allocU(256*512); ushort* w2l  = allocU(256*512);
    ushort* wh3h = allocU(128*256); ushort* wh3l = allocU(128*256);
    ushort* w4h  = allocU(32*128);  ushort* w4l  = allocU(32*128);
    float* y38    = alloc(524288);
    float* mbuf   = alloc(65536);
    float* gmaxb  = alloc(8192);
    float* G1     = alloc(8192);
    float* A1     = alloc(512);
    float* s1 = alloc(64);  float* t1 = alloc(64);
    float* s3 = alloc(512); float* t3 = alloc(512);
    float* sh1 = alloc(512); float* th1 = alloc(512);
    float* sh2 = alloc(256); float* th2 = alloc(256);
    float* sh3 = alloc(128); float* th3 = alloc(128);
    float* part1  = alloc(32768);
    float* part3  = alloc(512*1536);
    float* parth1 = alloc(512*1024);
    float* parth2 = alloc(512*512);
    float* parth3 = alloc(512*256);
    float* pre2   = alloc(16777216);
    float* pre3   = alloc(8388608);   // (128, 65536) fp32
    float4* sxp   = (float4*)alloc(65536UL*4);   // sorted coords (B,4096) float4
    int* sidxg    = (int*)alloc(65536);          // sorted orig indices

    k_wsplit_all<<<912, 256, 0, stream>>>(w3, hw1, hw2, hw3, hw4,
                                          w3h, w3l, w1eh, w1el, w2h, w2l,
                                          wh3h, wh3l, w4h, w4l);
    k_sortx<<<16, 1024, 0, stream>>>(pts, sxp, sidxg);

    k_stats1<<<256, 256, 0, stream>>>(pts, w1, b1, part1);
    k_fin<<<64, 256, 0, stream>>>(part1, 256, 128, 64, g1, be1, s1, t1);
    k_lfeat2<<<256, 256, 0, stream>>>(pts, w1, b1, s1, t1, lfh, lfl);
    k_gemm64<0><<<512, 256, 0, stream>>>(lfh, lfl, w3h, w3l, b3, nullptr, nullptr, nullptr, part3, y38);
    k_fin<<<512, 256, 0, stream>>>(part3, 512, 1536, 512, g3, be3, s3, t3);
    k_fin3b<<<16, 512, 0, stream>>>(part3, s3, t3, gmaxb);
    k_a1g1<<<34, 256, 0, stream>>>(hw1, gmaxb, A1, G1);
    k_knn<<<512, 1024, 0, stream>>>(sxp, sidxg, y38, s3, t3, mbuf);
    k_gemm64<1><<<512, 256, 0, stream>>>(lfh, lfl, w1eh, w1el, hb1, A1, G1, mbuf, parth1, nullptr);
    k_fin<<<512, 256, 0, stream>>>(parth1, 512, 1024, 512, hg1, hbe1, sh1, th1);
    k_h2f<<<512, 256, 0, stream>>>(lfh, lfl, w1eh, w1el, w2h, w2l, hb1, A1, G1, mbuf,
                                   sh1, th1, hb2, pre2, parth2);
    k_fin<<<256, 256, 0, stream>>>(parth2, 512, 512, 256, hg2, hbe2, sh2, th2);
    k_h3s<<<512, 256, 0, stream>>>(pre2, sh2, th2, wh3h, wh3l, hb3, parth3, pre3);
    k_fin<<<128, 256, 0, stream>>>(parth3, 512, 256, 128, hg3, hbe3, sh3, th3);
    k_h4l<<<1024, 256, 0, stream>>>(pre3, sh3, th3, hw4, hb4, (float*)d_out);
}

// Round 19
// 410.036 us; speedup vs baseline: 1.1584x; 1.1584x over previous
//
#include <hip/hip_runtime.h>
#include <hip/hip_bf16.h>
#include <math.h>

typedef __attribute__((ext_vector_type(8))) short short8;
typedef __attribute__((ext_vector_type(16))) float f32x16;

__device__ inline f32x16 mfma32(short8 a, short8 b, f32x16 c) {
    return __builtin_amdgcn_mfma_f32_32x32x16_bf16(a, b, c, 0, 0, 0);
}

__device__ inline void bsplit(float x, ushort& h, ushort& l) {
    __hip_bfloat16 bh = __float2bfloat16(x);
    float hf = __bfloat162float(bh);
    __hip_bfloat16 bl = __float2bfloat16(x - hf);
    h = *reinterpret_cast<ushort*>(&bh);
    l = *reinterpret_cast<ushort*>(&bl);
}

// inverse of the IEEE-monotone u32 map mp = db ^ (0x80000000 | (db>>31 arith))
__device__ inline float unmap_f(unsigned int mp) {
    unsigned int db = mp ^ (0x80000000u | (unsigned int)((int)(~mp) >> 31));
    return __uint_as_float(db);
}

// ---------------------------------------------------------------------------
// Fused weight convert: all five W[o][k] -> hi/lo bf16 planes in one launch
__global__ void k_wsplit_all(
    const float* __restrict__ w3s, const float* __restrict__ hw1,
    const float* __restrict__ hw2, const float* __restrict__ hw3,
    const float* __restrict__ hw4,
    ushort* __restrict__ w3h, ushort* __restrict__ w3l,
    ushort* __restrict__ w1eh, ushort* __restrict__ w1el,
    ushort* __restrict__ w2h, ushort* __restrict__ w2l,
    ushort* __restrict__ wh3h, ushort* __restrict__ wh3l,
    ushort* __restrict__ w4h, ushort* __restrict__ w4l) {
    int i = blockIdx.x * 256 + threadIdx.x;
    const float* src; int rs, co, Ms, K, base; ushort *hi, *lo;
    if (i < 32768)       { src = w3s; rs = 64;   co = 0;   Ms = 512; K = 64;  hi = w3h;  lo = w3l;  base = 0; }
    else if (i < 65536)  { src = hw1; rs = 1088; co = 512; Ms = 512; K = 64;  hi = w1eh; lo = w1el; base = 32768; }
    else if (i < 196608) { src = hw2; rs = 512;  co = 0;   Ms = 256; K = 512; hi = w2h;  lo = w2l;  base = 65536; }
    else if (i < 229376) { src = hw3; rs = 256;  co = 0;   Ms = 128; K = 256; hi = wh3h; lo = wh3l; base = 196608; }
    else if (i < 233472) { src = hw4; rs = 128;  co = 0;   Ms = 6;   K = 128; hi = w4h;  lo = w4l;  base = 229376; }
    else return;
    int li = i - base;
    int o = li / K, k = li - o * K;
    float x = (o < Ms) ? src[(size_t)o * rs + co + k] : 0.f;
    ushort h, l;
    bsplit(x, h, l);
    hi[li] = h; lo[li] = l;
}

// ---------------------------------------------------------------------------
// Layer 1 stats
__global__ void k_stats1(const float* __restrict__ pts, const float* __restrict__ w1,
                         const float* __restrict__ b1, float* __restrict__ part1) {
    __shared__ float sw[256];
    __shared__ float wred[2][4][64];
    int t = threadIdx.x;
    if (t < 192) sw[t] = w1[t];
    if (t < 64) sw[192 + t] = b1[t];
    __syncthreads();
    int g = blockIdx.x * 256 + t;
    float p0 = pts[g*3], p1 = pts[g*3+1], p2 = pts[g*3+2];
    int lane = t & 63, wv = t >> 6;
    for (int c = 0; c < 64; c++) {
        float y = fmaf(sw[c*3+2], p2, fmaf(sw[c*3+1], p1, fmaf(sw[c*3], p0, sw[192+c])));
        float s = y, q = y * y;
        #pragma unroll
        for (int o = 32; o > 0; o >>= 1) { s += __shfl_down(s, o); q += __shfl_down(q, o); }
        if (lane == 0) { wred[0][wv][c] = s; wred[1][wv][c] = q; }
    }
    __syncthreads();
    if (t < 64) {
        float s = wred[0][0][t] + wred[0][1][t] + wred[0][2][t] + wred[0][3][t];
        float q = wred[1][0][t] + wred[1][1][t] + wred[1][2][t] + wred[1][3][t];
        part1[blockIdx.x * 128 + t] = s;
        part1[blockIdx.x * 128 + 64 + t] = q;
    }
}

// Generic BN-stat finalize
__global__ void k_fin(const float* __restrict__ part, int count, int stride, int sqoff,
                      const float* __restrict__ g, const float* __restrict__ be,
                      float* __restrict__ sout, float* __restrict__ tout) {
    int c = blockIdx.x, t = threadIdx.x;
    float s = 0.f, q = 0.f;
    for (int w = t; w < count; w += 256) { s += part[(size_t)w*stride + c]; q += part[(size_t)w*stride + sqoff + c]; }
    __shared__ float rs[4], rq[4];
    int lane = t & 63, wv = t >> 6;
    #pragma unroll
    for (int o = 32; o > 0; o >>= 1) { s += __shfl_down(s, o); q += __shfl_down(q, o); }
    if (lane == 0) { rs[wv] = s; rq[wv] = q; }
    __syncthreads();
    if (t == 0) {
        s = rs[0] + rs[1] + rs[2] + rs[3];
        q = rq[0] + rq[1] + rq[2] + rq[3];
        float mean = s / 65536.f;
        float var = q / 65536.f - mean * mean;
        float sc = g[c] * rsqrtf(var + 1e-5f);
        sout[c] = sc;
        tout[c] = be[c] - mean * sc;
    }
}

// l_feat bf16 hi/lo planes, layout [n][64]
__global__ void k_lfeat2(const float* __restrict__ pts, const float* __restrict__ w1,
                         const float* __restrict__ b1, const float* __restrict__ s1,
                         const float* __restrict__ t1, ushort* __restrict__ lfh,
                         ushort* __restrict__ lfl) {
    __shared__ float sw[256], ss[64], st[64];
    int t = threadIdx.x;
    if (t < 192) sw[t] = w1[t];
    if (t < 64) { sw[192+t] = b1[t]; ss[t] = s1[t]; st[t] = t1[t]; }
    __syncthreads();
    int g = blockIdx.x * 256 + t;
    float p0 = pts[g*3], p1 = pts[g*3+1], p2 = pts[g*3+2];
    for (int c0 = 0; c0 < 64; c0 += 8) {
        union { short8 v; ushort u[8]; } H, L;
        #pragma unroll
        for (int j = 0; j < 8; j++) {
            int c = c0 + j;
            float y = fmaf(sw[c*3+2], p2, fmaf(sw[c*3+1], p1, fmaf(sw[c*3], p0, sw[192+c])));
            float a = fmaxf(fmaf(ss[c], y, st[c]), 0.f);
            bsplit(a, H.u[j], L.u[j]);
        }
        *(short8*)(lfh + (size_t)g*64 + c0) = H.v;
        *(short8*)(lfl + (size_t)g*64 + c0) = L.v;
    }
}

// ---------------------------------------------------------------------------
// K=64 MFMA GEMM: MODE 0 = conv3 (stats s/q/max + y38), MODE 1 = h1 stats
template<int MODE>
__global__ __launch_bounds__(256, 2) void k_gemm64(
    const ushort* __restrict__ Bhi, const ushort* __restrict__ Blo,
    const ushort* __restrict__ Ahi, const ushort* __restrict__ Alo,
    const float* __restrict__ bias, const float* __restrict__ A1,
    const float* __restrict__ G1, const float* __restrict__ mb,
    float* __restrict__ part, float* __restrict__ y38) {
    __shared__ ushort sbh[128*64], sbl[128*64];
    __shared__ float sPb[512], sPa[512];
    int t = threadIdx.x, pb = blockIdx.x;
    int gn0 = pb * 128, b = pb >> 5;
    for (int i = t; i < 512; i += 256) {
        float bb = bias[i];
        if (MODE) bb += G1[(b<<9) + i];
        sPb[i] = bb;
        sPa[i] = MODE ? A1[i] : 0.f;
    }
    for (int it = 0; it < 4; it++) {
        int s = it*256 + t;
        int n = s >> 3, c16 = s & 7;
        int off = (c16*16) ^ ((n & 7) << 4);
        int sb8 = (it*256 + (t & 192)) * 8;
        __builtin_amdgcn_global_load_lds((const char*)Bhi + (size_t)(gn0+n)*128 + off, &sbh[sb8], 16, 0, 0);
        __builtin_amdgcn_global_load_lds((const char*)Blo + (size_t)(gn0+n)*128 + off, &sbl[sb8], 16, 0, 0);
    }
    __syncthreads();
    int lane = t & 63, wv = t >> 6, m = lane & 31, kg = lane >> 5;
    for (int ct = 0; ct < 4; ct++) {
        int ch0 = wv*128 + ct*32;
        short8 ah[4], al[4];
        #pragma unroll
        for (int ks = 0; ks < 4; ks++) {
            ah[ks] = *(const short8*)(Ahi + (size_t)(ch0+m)*64 + ks*16 + kg*8);
            al[ks] = *(const short8*)(Alo + (size_t)(ch0+m)*64 + ks*16 + kg*8);
        }
        float ssum[16] = {}, ssq[16] = {}, smx[16];
        #pragma unroll
        for (int r = 0; r < 16; r++) smx[r] = -__builtin_inff();
        for (int pt = 0; pt < 4; pt++) {
            int n = pt*32 + m;
            f32x16 acc = {};
            #pragma unroll
            for (int ks = 0; ks < 4; ks++) {
                int off = ((ks*16 + kg*8)*2) ^ ((n & 7) << 4);
                short8 bh = *(const short8*)((const char*)sbh + n*128 + off);
                short8 bl = *(const short8*)((const char*)sbl + n*128 + off);
                acc = mfma32(ah[ks], bh, acc);
                acc = mfma32(ah[ks], bl, acc);
                acc = mfma32(al[ks], bh, acc);
            }
            float mval = MODE ? mb[gn0 + n] : 0.f;
            #pragma unroll
            for (int r = 0; r < 16; r++) {
                int chr = ch0 + (r&3) + 8*(r>>2) + 4*kg;
                float v = acc[r] + sPb[chr] + (MODE ? sPa[chr]*mval : 0.f);
                ssum[r] += v; ssq[r] = fmaf(v, v, ssq[r]);
                if (MODE == 0) {
                    smx[r] = fmaxf(smx[r], v);
                    if (wv == 0 && ct == 0 && r < 4) {
                        int c8 = (r&3) + 4*kg;  // 0..7
                        y38[(size_t)c8*65536 + gn0 + n] = v;
                    }
                }
            }
        }
        #pragma unroll
        for (int r = 0; r < 16; r++) {
            float s = ssum[r], q = ssq[r], x = smx[r];
            #pragma unroll
            for (int o = 16; o > 0; o >>= 1) {
                s += __shfl_xor(s, o); q += __shfl_xor(q, o);
                if (MODE == 0) x = fmaxf(x, __shfl_xor(x, o));
            }
            if (m == 0) {
                int chr = ch0 + (r&3) + 8*(r>>2) + 4*kg;
                if (MODE == 0) {
                    part[(size_t)pb*1536 + chr] = s;
                    part[(size_t)pb*1536 + 512 + chr] = q;
                    part[(size_t)pb*1536 + 1024 + chr] = x;
                } else {
                    part[(size_t)pb*1024 + chr] = s;
                    part[(size_t)pb*1024 + 512 + chr] = q;
                }
            }
        }
    }
}

// gmax[b,c] = relu(s3*max + t3); part3 blocks 32 per batch
__global__ void k_fin3b(const float* __restrict__ part3, const float* __restrict__ s3,
                        const float* __restrict__ t3, float* __restrict__ gmaxb) {
    int b = blockIdx.x, c = threadIdx.x;
    float mx = -__builtin_inff();
    for (int i = 0; i < 32; i++) mx = fmaxf(mx, part3[(size_t)(b*32+i)*1536 + 1024 + c]);
    gmaxb[(b<<9)+c] = fmaxf(fmaf(s3[c], mx, t3[c]), 0.f);
}

// A1/G1 v2: coalesced float4 reads; summation order identical to v1
__global__ void k_a1g1(const float* __restrict__ hw1, const float* __restrict__ gmaxb,
                       float* __restrict__ A1, float* __restrict__ G1) {
    __shared__ float sg[512];
    int blk = blockIdx.x, t = threadIdx.x;
    if (blk < 32) {
        int b = blk >> 1;
        for (int i = t; i < 512; i += 256) sg[i] = gmaxb[(b<<9)+i];
        __syncthreads();
        int o = (blk & 1)*256 + t;
        float s = 0.f;
        for (int c4 = 0; c4 < 128; c4++) {
            float4 w = *(const float4*)&hw1[(size_t)o*1088 + 576 + c4*4];
            s = fmaf(w.x, sg[c4*4],   s);
            s = fmaf(w.y, sg[c4*4+1], s);
            s = fmaf(w.z, sg[c4*4+2], s);
            s = fmaf(w.w, sg[c4*4+3], s);
        }
        G1[(b<<9)+o] = s;
    } else {
        int o = (blk - 32)*256 + t;
        float s = 0.f;
        for (int c4 = 0; c4 < 128; c4++) {
            float4 w = *(const float4*)&hw1[(size_t)o*1088 + c4*4];
            s += w.x; s += w.y; s += w.z; s += w.w;
        }
        A1[o] = s;
    }
}

// ---------------------------------------------------------------------------
// KNN v11 (round-15/16 exact code, measured 148 us): wave-per-4-queries x 2
// passes, shared candidate load; bitonic init + pruned DPP-insert.
__global__ __launch_bounds__(1024, 8)
void k_knn(const float* __restrict__ pts, const float* __restrict__ y38,
           const float* __restrict__ s3, const float* __restrict__ t3,
           float* __restrict__ mbuf) {
    __shared__ float4 sp[4096];   // 64 KB: all candidates of this batch
    int t = threadIdx.x, blk = blockIdx.x;
    int b = blk >> 5;
    int lane = t & 63, wv = t >> 6;
    const float* pb = pts + (size_t)b * 4096 * 3;
    for (int i = t; i < 4096; i += 1024) {
        float c0 = pb[i*3], c1 = pb[i*3+1], c2 = pb[i*3+2];
        float cw = __fadd_rn(__fadd_rn(__fmul_rn(c0,c0), __fmul_rn(c1,c1)), __fmul_rn(c2,c2));
        sp[i] = make_float4(c0, c1, c2, cw);
    }
    __syncthreads();
    const int NINF = 0xff800000;  // -inf bits
    int qbase = (blk & 31) * 128 + wv * 8;
    for (int pass = 0; pass < 2; ++pass) {
        int qb = qbase + pass*4;
        float q0[4], q1[4], q2[4], qx2[4];
        #pragma unroll
        for (int qi = 0; qi < 4; qi++) {
            float4 qp = sp[qb + qi];              // uniform broadcast read
            q0[qi] = qp.x; q1[qi] = qp.y; q2[qi] = qp.z; qx2[qi] = qp.w;
        }
        float sd[4]; unsigned int si[4]; float thr[4];
        {
            float4 cp = sp[lane];
            #pragma unroll
            for (int qi = 0; qi < 4; qi++) {
                float dot = __fadd_rn(__fadd_rn(__fmul_rn(q0[qi],cp.x), __fmul_rn(q1[qi],cp.y)), __fmul_rn(q2[qi],cp.z));
                float d = __fsub_rn(__fadd_rn(qx2[qi], cp.w), __fmul_rn(2.f, dot));
                unsigned int db = __float_as_uint(d);
                unsigned int mp = db ^ (0x80000000u | (unsigned int)((int)db >> 31));
                unsigned long long key = ((unsigned long long)mp << 32) | (unsigned int)lane;
                #pragma unroll
                for (int k = 2; k <= 64; k <<= 1) {
                    #pragma unroll
                    for (int jj = k >> 1; jj >= 1; jj >>= 1) {
                        unsigned long long pk = __shfl_xor(key, jj);
                        bool up = ((lane & k) == 0);
                        bool lower = ((lane & jj) == 0);
                        bool keepmin = (lower == up);
                        unsigned long long mn = (pk < key) ? pk : key;
                        unsigned long long mx = (pk < key) ? key : pk;
                        key = keepmin ? mn : mx;
                    }
                }
                sd[qi] = unmap_f((unsigned int)(key >> 32));
                si[qi] = (unsigned int)key;
                thr[qi] = __shfl(sd[qi], 7);
            }
        }
        for (int j = 1; j < 64; j++) {
            float4 cp = sp[j*64 + lane];
            #pragma unroll
            for (int qi = 0; qi < 4; qi++) {
                float dot = __fadd_rn(__fadd_rn(__fmul_rn(q0[qi],cp.x), __fmul_rn(q1[qi],cp.y)), __fmul_rn(q2[qi],cp.z));
                float d = __fsub_rn(__fadd_rn(qx2[qi], cp.w), __fmul_rn(2.f, dot));
                unsigned long long mask = __ballot(d < thr[qi]);
                if (mask != 0ull) {
                    do {
                        int src = __ffsll(mask) - 1;
                        float db = __uint_as_float(__builtin_amdgcn_readlane(__float_as_uint(d), src));
                        unsigned int mb_ = (unsigned int)(j*64 + src);
                        float pd = __int_as_float(__builtin_amdgcn_update_dpp(
                            NINF, __float_as_int(sd[qi]), 0x111, 0xf, 0xf, false));  // row_shr:1
                        unsigned int pi = (unsigned int)__builtin_amdgcn_update_dpp(
                            0, (int)si[qi], 0x111, 0xf, 0xf, false);
                        bool keep = (sd[qi] <= db);
                        bool pk = (pd <= db);
                        sd[qi] = keep ? sd[qi] : (pk ? db : pd);
                        si[qi] = keep ? si[qi] : (pk ? mb_ : pi);
                        mask &= (mask - 1ull);
                    } while (mask != 0ull);
                    thr[qi] = __shfl(sd[qi], 7);
                }
            }
        }
        if (lane < 8) {
            #pragma unroll
            for (int qi = 0; qi < 4; qi++) {
                float y = y38[(size_t)lane*65536 + (b<<12) + (si[qi] & 4095)];
                float mv = fmaxf(fmaf(s3[lane], y, t3[lane]), 0.f);
                mv = fmaxf(mv, __shfl_xor(mv, 1));
                mv = fmaxf(mv, __shfl_xor(mv, 2));
                mv = fmaxf(mv, __shfl_xor(mv, 4));
                if (lane == 0) mbuf[(b<<12) + qb + qi] = mv;
            }
        }
    }
}

// ---------------------------------------------------------------------------
// h2 FUSED: per 64-ch K-chunk, phase-1 computes a1 into swizzled LDS;
// phase-2 accumulates pre2 = hw2 @ a1. grid 512 x 256thr, 128 pts/block.
__global__ __launch_bounds__(256, 2) void k_h2f(
    const ushort* __restrict__ lfh, const ushort* __restrict__ lfl,
    const ushort* __restrict__ W1hi, const ushort* __restrict__ W1lo,
    const ushort* __restrict__ W2hi, const ushort* __restrict__ W2lo,
    const float* __restrict__ hb1, const float* __restrict__ A1g,
    const float* __restrict__ G1g, const float* __restrict__ mb,
    const float* __restrict__ sh1, const float* __restrict__ th1,
    const float* __restrict__ hb2,
    float* __restrict__ pre2, float* __restrict__ parth2) {
    __shared__ ushort sLh[128*64], sLl[128*64];   // lf tile, 16+16 KB
    __shared__ ushort a1h[128*64], a1l[128*64];   // a1 chunk, 16+16 KB
    __shared__ float sP0[512], sP1[512], sSh[512];
    int t = threadIdx.x, pb = blockIdx.x;
    int gn0 = pb * 128, b = pb >> 5;
    for (int i = t; i < 512; i += 256) {
        float s = sh1[i];
        sP0[i] = fmaf(s, hb1[i] + G1g[(b<<9)+i], th1[i]);
        sP1[i] = s * A1g[i];
        sSh[i] = s;
    }
    for (int it = 0; it < 4; it++) {
        int s = it*256 + t;
        int n = s >> 3, c16 = s & 7;
        int off = (c16*16) ^ ((n & 7) << 4);
        int sb8 = (it*256 + (t & 192)) * 8;
        __builtin_amdgcn_global_load_lds((const char*)lfh + (size_t)(gn0+n)*128 + off, &sLh[sb8], 16, 0, 0);
        __builtin_amdgcn_global_load_lds((const char*)lfl + (size_t)(gn0+n)*128 + off, &sLl[sb8], 16, 0, 0);
    }
    __syncthreads();
    int lane = t & 63, wv = t >> 6, m = lane & 31, kg = lane >> 5;
    int pn = wv*32 + m;
    float mval = mb[gn0 + pn];
    f32x16 acc0[4] = {}, acc1[4] = {};
    for (int ch = 0; ch < 8; ch++) {
        #pragma unroll
        for (int cht = 0; cht < 2; cht++) {
            int cch = ch*64 + cht*32;
            f32x16 acc = {};
            #pragma unroll
            for (int ks = 0; ks < 4; ks++) {
                short8 ah = *(const short8*)(W1hi + (size_t)(cch+m)*64 + ks*16 + kg*8);
                short8 al = *(const short8*)(W1lo + (size_t)(cch+m)*64 + ks*16 + kg*8);
                int off = ((ks*16 + kg*8)*2) ^ ((m & 7) << 4);
                short8 bh = *(const short8*)((const char*)sLh + pn*128 + off);
                short8 bl = *(const short8*)((const char*)sLl + pn*128 + off);
                acc = mfma32(ah, bh, acc);
                acc = mfma32(ah, bl, acc);
                acc = mfma32(al, bh, acc);
            }
            #pragma unroll
            for (int q = 0; q < 4; q++) {
                ushort hs[4], ls[4];
                #pragma unroll
                for (int i = 0; i < 4; i++) {
                    int r = q*4 + i;
                    int chr = cch + i + 8*q + 4*kg;
                    float a = fmaxf(fmaf(sSh[chr], acc[r], sP0[chr] + sP1[chr]*mval), 0.f);
                    bsplit(a, hs[i], ls[i]);
                }
                int chb = cht*32 + 8*q + 4*kg;
                int off = (chb*2) ^ ((m & 7) << 4);
                uint2 vh, vl;
                vh.x = (uint)hs[0] | ((uint)hs[1] << 16); vh.y = (uint)hs[2] | ((uint)hs[3] << 16);
                vl.x = (uint)ls[0] | ((uint)ls[1] << 16); vl.y = (uint)ls[2] | ((uint)ls[3] << 16);
                *(uint2*)((char*)a1h + pn*128 + off) = vh;
                *(uint2*)((char*)a1l + pn*128 + off) = vl;
            }
        }
        __syncthreads();
        #pragma unroll
        for (int ks = 0; ks < 4; ks++) {
            int koc = ks*16 + kg*8;
            int kglob = ch*64 + koc;
            short8 w0h = *(const short8*)(W2hi + (size_t)(wv*64+m)*512 + kglob);
            short8 w0l = *(const short8*)(W2lo + (size_t)(wv*64+m)*512 + kglob);
            short8 w1h = *(const short8*)(W2hi + (size_t)(wv*64+32+m)*512 + kglob);
            short8 w1l = *(const short8*)(W2lo + (size_t)(wv*64+32+m)*512 + kglob);
            #pragma unroll
            for (int pt = 0; pt < 4; pt++) {
                int n = pt*32 + m;
                int off = (koc*2) ^ ((n & 7) << 4);
                short8 bh = *(const short8*)((const char*)a1h + n*128 + off);
                short8 bl = *(const short8*)((const char*)a1l + n*128 + off);
                acc0[pt] = mfma32(w0h, bh, acc0[pt]);
                acc1[pt] = mfma32(w1h, bh, acc1[pt]);
                acc0[pt] = mfma32(w0h, bl, acc0[pt]);
                acc1[pt] = mfma32(w1h, bl, acc1[pt]);
                acc0[pt] = mfma32(w0l, bh, acc0[pt]);
                acc1[pt] = mfma32(w1l, bh, acc1[pt]);
            }
        }
        __syncthreads();
    }
    #pragma unroll
    for (int ti = 0; ti < 2; ti++) {
        #pragma unroll
        for (int r = 0; r < 16; r++) {
            int chr = wv*64 + ti*32 + (r&3) + 8*(r>>2) + 4*kg;
            float hb = hb2[chr];
            float s = 0.f, q = 0.f;
            #pragma unroll
            for (int pt = 0; pt < 4; pt++) {
                float v = (ti ? acc1[pt][r] : acc0[pt][r]) + hb;
                pre2[(size_t)chr*65536 + gn0 + pt*32 + m] = v;
                s += v; q = fmaf(v, v, q);
            }
            #pragma unroll
            for (int o = 16; o > 0; o >>= 1) { s += __shfl_xor(s, o); q += __shfl_xor(q, o); }
            if (m == 0) {
                parth2[(size_t)pb*512 + chr] = s;
                parth2[(size_t)pb*512 + 256 + chr] = q;
            }
        }
    }
}

// ---------------------------------------------------------------------------
// h3 stats + pre3 materialize: pre3 = hw3 @ a2 + hb3 written to global [c][n].
__global__ __launch_bounds__(256, 2) void k_h3s(
    const float* __restrict__ pre2, const float* __restrict__ sh2,
    const float* __restrict__ th2,
    const ushort* __restrict__ W3hi, const ushort* __restrict__ W3lo,
    const float* __restrict__ hb3, float* __restrict__ parth3,
    float* __restrict__ pre3) {
    __shared__ ushort sbh[32*256], sbl[32*256];   // 16+16 KB
    __shared__ float ft[128*36];                  // 18 KB padded fp32 tile
    __shared__ float sS2[256], sT2[256];
    int t = threadIdx.x, pb = blockIdx.x;
    sS2[t] = sh2[t]; sT2[t] = th2[t];
    int lane = t & 63, wv = t >> 6, m = lane & 31, kg = lane >> 5;
    int ch0 = wv * 32;
    int cn = t & 31, cgq = t >> 5;
    float bhr[16];
    #pragma unroll
    for (int r = 0; r < 16; r++) bhr[r] = hb3[ch0 + (r&3) + 8*(r>>2) + 4*kg];
    float ssum[16] = {}, ssq[16] = {};
    for (int pt = 0; pt < 4; pt++) {
        int gn0 = pb*128 + pt*32;
        for (int h = 0; h < 2; h++) {
            __syncthreads();
            #pragma unroll
            for (int i = 0; i < 4; i++) {
                int idx = i*256 + t;
                int row = idx >> 3, c4 = idx & 7;
                float4 v = *(const float4*)(pre2 + (size_t)(h*128+row)*65536 + gn0 + c4*4);
                float* dst = &ft[row*36 + c4*4];
                dst[0] = v.x; dst[1] = v.y; dst[2] = v.z; dst[3] = v.w;
            }
            __syncthreads();
            #pragma unroll
            for (int i4 = 0; i4 < 4; i4++) {
                int cl0 = cgq*16 + i4*4;
                int cg0 = h*128 + cl0;
                ushort hs[4], ls[4];
                #pragma unroll
                for (int i = 0; i < 4; i++) {
                    float v = fmaxf(fmaf(sS2[cg0+i], ft[(cl0+i)*36 + cn], sT2[cg0+i]), 0.f);
                    bsplit(v, hs[i], ls[i]);
                }
                int off = cn*512 + (((cg0 >> 3)*16) ^ ((cn & 15) << 4)) + (cg0 & 7)*2;
                uint2 vh, vl;
                vh.x = (uint)hs[0] | ((uint)hs[1] << 16); vh.y = (uint)hs[2] | ((uint)hs[3] << 16);
                vl.x = (uint)ls[0] | ((uint)ls[1] << 16); vl.y = (uint)ls[2] | ((uint)ls[3] << 16);
                *(uint2*)((char*)sbh + off) = vh;
                *(uint2*)((char*)sbl + off) = vl;
            }
        }
        __syncthreads();
        f32x16 acc = {};
        for (int ks = 0; ks < 16; ks++) {
            int ko = ks*16 + kg*8;
            int off = (ko*2) ^ ((m & 15) << 4);
            short8 bh = *(const short8*)((const char*)sbh + m*512 + off);
            short8 bl = *(const short8*)((const char*)sbl + m*512 + off);
            short8 ah = *(const short8*)(W3hi + (size_t)(ch0+m)*256 + ko);
            short8 al = *(const short8*)(W3lo + (size_t)(ch0+m)*256 + ko);
            acc = mfma32(ah, bh, acc);
            acc = mfma32(ah, bl, acc);
            acc = mfma32(al, bh, acc);
        }
        #pragma unroll
        for (int r = 0; r < 16; r++) {
            float v = acc[r] + bhr[r];
            int chr = ch0 + (r&3) + 8*(r>>2) + 4*kg;
            pre3[(size_t)chr*65536 + gn0 + m] = v;
            ssum[r] += v; ssq[r] = fmaf(v, v, ssq[r]);
        }
    }
    #pragma unroll
    for (int r = 0; r < 16; r++) {
        float s = ssum[r], q = ssq[r];
        #pragma unroll
        for (int o = 16; o > 0; o >>= 1) { s += __shfl_xor(s, o); q += __shfl_xor(q, o); }
        if (m == 0) {
            int chr = ch0 + (r&3) + 8*(r>>2) + 4*kg;
            parth3[(size_t)pb*256 + chr] = s;
            parth3[(size_t)pb*256 + 128 + chr] = q;
        }
    }
}

// ---------------------------------------------------------------------------
// h4 light: a3 = relu(sh3*pre3 + th3); out = hw4 @ a3 + hb4 (fp32 dot).
__global__ __launch_bounds__(256) void k_h4l(
    const float* __restrict__ pre3, const float* __restrict__ sh3,
    const float* __restrict__ th3, const float* __restrict__ hw4,
    const float* __restrict__ hb4, float* __restrict__ out) {
    __shared__ float a3[128*66];     // padded [c][66]
    __shared__ float sW[6*128];
    __shared__ float sB[8];
    int t = threadIdx.x, pb = blockIdx.x;
    int n0 = pb * 64;
    for (int i = t; i < 768; i += 256) sW[i] = hw4[i];
    if (t < 6) sB[t] = hb4[t];
    #pragma unroll
    for (int k = 0; k < 32; k++) {
        int i = k*256 + t;
        int c = i >> 6, col = i & 63;
        float v = pre3[(size_t)c*65536 + n0 + col];
        a3[c*66 + col] = fmaxf(fmaf(sh3[c], v, th3[c]), 0.f);
    }
    __syncthreads();
    int p = t & 63, grp = t >> 6;
    if (grp < 3) {
        float a0 = sB[grp*2], a1 = sB[grp*2+1];
        const float* w0 = &sW[(grp*2)*128];
        const float* w1 = &sW[(grp*2+1)*128];
        #pragma unroll 4
        for (int c = 0; c < 128; c++) {
            float x = a3[c*66 + p];
            a0 = fmaf(w0[c], x, a0);
            a1 = fmaf(w1[c], x, a1);
        }
        out[(size_t)(n0+p)*6 + grp*2]     = a0;
        out[(size_t)(n0+p)*6 + grp*2 + 1] = a1;
    }
}

extern "C" void kernel_launch(void* const* d_in, const int* in_sizes, int n_in,
                              void* d_out, int out_size, void* d_ws, size_t ws_size,
                              hipStream_t stream) {
    const float* pts  = (const float*)d_in[0];
    const float* w1   = (const float*)d_in[1];
    const float* b1   = (const float*)d_in[2];
    const float* g1   = (const float*)d_in[3];
    const float* be1  = (const float*)d_in[4];
    const float* w3   = (const float*)d_in[5];
    const float* b3   = (const float*)d_in[6];
    const float* g3   = (const float*)d_in[7];
    const float* be3  = (const float*)d_in[8];
    const float* hw1  = (const float*)d_in[9];
    const float* hb1  = (const float*)d_in[10];
    const float* hg1  = (const float*)d_in[11];
    const float* hbe1 = (const float*)d_in[12];
    const float* hw2  = (const float*)d_in[13];
    const float* hb2  = (const float*)d_in[14];
    const float* hg2  = (const float*)d_in[15];
    const float* hbe2 = (const float*)d_in[16];
    const float* hw3  = (const float*)d_in[17];
    const float* hb3  = (const float*)d_in[18];
    const float* hg3  = (const float*)d_in[19];
    const float* hbe3 = (const float*)d_in[20];
    const float* hw4  = (const float*)d_in[21];
    const float* hb4  = (const float*)d_in[22];
    (void)in_sizes; (void)n_in; (void)out_size; (void)ws_size;

    float* W = (float*)d_ws;
    size_t off = 0;
    auto alloc = [&](size_t n) { float* p = W + off; off += n; return p; };
    auto allocU = [&](size_t nshorts) { return (ushort*)alloc((nshorts + 1) / 2); };

    ushort* lfh  = allocU(65536UL*64);
    ushort* lfl  = allocU(65536UL*64);
    ushort* w3h  = allocU(512*64);  ushort* w3l  = allocU(512*64);
    ushort* w1eh = allocU(512*64);  ushort* w1el = allocU(512*64);
    ushort* w2h  = allocU(256*512); ushort* w2l  = allocU(256*512);
    ushort* wh3h = allocU(128*256); ushort* wh3l = allocU(128*256);
    ushort* w4h  = allocU(32*128);  ushort* w4l  = allocU(32*128);
    float* y38    = alloc(524288);
    float* mbuf   = alloc(65536);
    float* gmaxb  = alloc(8192);
    float* G1     = alloc(8192);
    float* A1     = alloc(512);
    float* s1 = alloc(64);  float* t1 = alloc(64);
    float* s3 = alloc(512); float* t3 = alloc(512);
    float* sh1 = alloc(512); float* th1 = alloc(512);
    float* sh2 = alloc(256); float* th2 = alloc(256);
    float* sh3 = alloc(128); float* th3 = alloc(128);
    float* part1  = alloc(32768);
    float* part3  = alloc(512*1536);
    float* parth1 = alloc(512*1024);
    float* parth2 = alloc(512*512);
    float* parth3 = alloc(512*256);
    float* pre2   = alloc(16777216);
    float* pre3   = alloc(8388608);   // (128, 65536) fp32

    k_wsplit_all<<<912, 256, 0, stream>>>(w3, hw1, hw2, hw3, hw4,
                                          w3h, w3l, w1eh, w1el, w2h, w2l,
                                          wh3h, wh3l, w4h, w4l);

    k_stats1<<<256, 256, 0, stream>>>(pts, w1, b1, part1);
    k_fin<<<64, 256, 0, stream>>>(part1, 256, 128, 64, g1, be1, s1, t1);
    k_lfeat2<<<256, 256, 0, stream>>>(pts, w1, b1, s1, t1, lfh, lfl);
    k_gemm64<0><<<512, 256, 0, stream>>>(lfh, lfl, w3h, w3l, b3, nullptr, nullptr, nullptr, part3, y38);
    k_fin<<<512, 256, 0, stream>>>(part3, 512, 1536, 512, g3, be3, s3, t3);
    k_fin3b<<<16, 512, 0, stream>>>(part3, s3, t3, gmaxb);
    k_a1g1<<<34, 256, 0, stream>>>(hw1, gmaxb, A1, G1);
    k_knn<<<512, 1024, 0, stream>>>(pts, y38, s3, t3, mbuf);
    k_gemm64<1><<<512, 256, 0, stream>>>(lfh, lfl, w1eh, w1el, hb1, A1, G1, mbuf, parth1, nullptr);
    k_fin<<<512, 256, 0, stream>>>(parth1, 512, 1024, 512, hg1, hbe1, sh1, th1);
    k_h2f<<<512, 256, 0, stream>>>(lfh, lfl, w1eh, w1el, w2h, w2l, hb1, A1, G1, mbuf,
                                   sh1, th1, hb2, pre2, parth2);
    k_fin<<<256, 256, 0, stream>>>(parth2, 512, 512, 256, hg2, hbe2, sh2, th2);
    k_h3s<<<512, 256, 0, stream>>>(pre2, sh2, th2, wh3h, wh3l, hb3, parth3, pre3);
    k_fin<<<128, 256, 0, stream>>>(parth3, 512, 256, 128, hg3, hbe3, sh3, th3);
    k_h4l<<<1024, 256, 0, stream>>>(pre3, sh3, th3, hw4, hb4, (float*)d_out);
}